// Round 1
// baseline (1011.849 us; speedup 1.0000x reference)
//
#include <hip/hip_runtime.h>
#include <math.h>

#define S_LEN 1024
#define DIMS  1024
#define NHEAD 16
#define HD    64
#define BATCH 2
#define MROWS (BATCH * S_LEN)   // 2048

// ---------------- LayerNorm (both local & globe in one pass) ----------------
__global__ __launch_bounds__(256) void ln2_kernel(
    const float* __restrict__ x,
    const float* __restrict__ ga, const float* __restrict__ ba,
    const float* __restrict__ gb, const float* __restrict__ bb,
    float* __restrict__ outA, float* __restrict__ outB)
{
    int row = blockIdx.x;
    int t = threadIdx.x;
    const float* xr = x + (size_t)row * DIMS;
    float4 v = *(const float4*)(xr + t * 4);
    float s  = v.x + v.y + v.z + v.w;
    float s2 = v.x * v.x + v.y * v.y + v.z * v.z + v.w * v.w;
#pragma unroll
    for (int o = 32; o > 0; o >>= 1) {
        s  += __shfl_down(s, o, 64);
        s2 += __shfl_down(s2, o, 64);
    }
    __shared__ float rs[4], rs2[4];
    int wid = t >> 6, lane = t & 63;
    if (lane == 0) { rs[wid] = s; rs2[wid] = s2; }
    __syncthreads();
    float S0 = rs[0] + rs[1] + rs[2] + rs[3];
    float S2 = rs2[0] + rs2[1] + rs2[2] + rs2[3];
    float mean = S0 * (1.0f / DIMS);
    float var  = S2 * (1.0f / DIMS) - mean * mean;
    float inv  = 1.0f / sqrtf(var + 1e-5f);
    float4 vga = *(const float4*)(ga + t * 4);
    float4 vba = *(const float4*)(ba + t * 4);
    float4 vgb = *(const float4*)(gb + t * 4);
    float4 vbb = *(const float4*)(bb + t * 4);
    float nx = (v.x - mean) * inv, ny = (v.y - mean) * inv;
    float nz = (v.z - mean) * inv, nw = (v.w - mean) * inv;
    float4 oa = make_float4(nx * vga.x + vba.x, ny * vga.y + vba.y,
                            nz * vga.z + vba.z, nw * vga.w + vba.w);
    float4 ob = make_float4(nx * vgb.x + vbb.x, ny * vgb.y + vbb.y,
                            nz * vgb.z + vbb.z, nw * vgb.w + vbb.w);
    *(float4*)(outA + (size_t)row * DIMS + t * 4) = oa;
    *(float4*)(outB + (size_t)row * DIMS + t * 4) = ob;
}

// ---------------- f32 GEMM: C[M,N] = A[M,K] @ W[N,K]^T (+bias) --------------
// grid (N/64, M/64), block 256, thread computes 4x4
__global__ __launch_bounds__(256) void gemm_f32(
    const float* __restrict__ A, int lda,
    const float* __restrict__ W, int ldw,
    const float* __restrict__ bias,
    float* __restrict__ C, int ldc,
    int K)
{
    __shared__ float As[16][68];
    __shared__ float Bs[16][68];
    int tid = threadIdx.x;
    int bm = blockIdx.y * 64, bn = blockIdx.x * 64;
    int tx = tid & 15, ty = tid >> 4;
    int lrow = tid >> 2;
    int lk   = (tid & 3) * 4;
    float acc[4][4] = {{0.f,0.f,0.f,0.f},{0.f,0.f,0.f,0.f},{0.f,0.f,0.f,0.f},{0.f,0.f,0.f,0.f}};
    const float* Aptr = A + (size_t)(bm + lrow) * lda + lk;
    const float* Wptr = W + (size_t)(bn + lrow) * ldw + lk;
    for (int kk = 0; kk < K; kk += 16) {
        float4 a = *(const float4*)(Aptr + kk);
        float4 b = *(const float4*)(Wptr + kk);
        __syncthreads();
        As[lk + 0][lrow] = a.x; As[lk + 1][lrow] = a.y;
        As[lk + 2][lrow] = a.z; As[lk + 3][lrow] = a.w;
        Bs[lk + 0][lrow] = b.x; Bs[lk + 1][lrow] = b.y;
        Bs[lk + 2][lrow] = b.z; Bs[lk + 3][lrow] = b.w;
        __syncthreads();
#pragma unroll
        for (int k = 0; k < 16; ++k) {
            float4 av = *(const float4*)&As[k][ty * 4];
            float4 bv = *(const float4*)&Bs[k][tx * 4];
            float ar[4] = {av.x, av.y, av.z, av.w};
            float br[4] = {bv.x, bv.y, bv.z, bv.w};
#pragma unroll
            for (int i = 0; i < 4; ++i)
#pragma unroll
                for (int j = 0; j < 4; ++j)
                    acc[i][j] += ar[i] * br[j];
        }
    }
    float4 bfrag = make_float4(0.f, 0.f, 0.f, 0.f);
    if (bias) bfrag = *(const float4*)(bias + bn + tx * 4);
#pragma unroll
    for (int i = 0; i < 4; ++i) {
        float4 o = make_float4(acc[i][0] + bfrag.x, acc[i][1] + bfrag.y,
                               acc[i][2] + bfrag.z, acc[i][3] + bfrag.w);
        *(float4*)(C + (size_t)(bm + ty * 4 + i) * ldc + bn + tx * 4) = o;
    }
}

// ---------------- attention: 4 q-rows per block, full softmax ---------------
// LOCAL: scale=span[1], keys k>=eff masked, out rows s>=eff zeroed
template <int LOCAL>
__global__ __launch_bounds__(256) void attn_kernel(
    const float* __restrict__ Q, const float* __restrict__ K,
    const float* __restrict__ V, float* __restrict__ O, int ldo,
    const float* __restrict__ span)
{
    __shared__ float sc[4][1024];
    __shared__ float qs[4][64];
    __shared__ float red[4][4];
    __shared__ float pacc[4][4][64];
    int b = blockIdx.z, h = blockIdx.y, s0 = blockIdx.x * 4;
    int tid = threadIdx.x;
    float scale; int eff;
    if (LOCAL) { scale = span[1]; eff = (int)span[0]; }
    else       { scale = 1.0f / 64.0f; eff = S_LEN; }
    {
        int r = tid >> 6, j = tid & 63;
        qs[r][j] = Q[(size_t)(b * S_LEN + s0 + r) * DIMS + h * HD + j];
    }
    __syncthreads();
    float mymax[4] = {-1e30f, -1e30f, -1e30f, -1e30f};
    const float* Kbase = K + (size_t)(b * S_LEN) * DIMS + h * HD;
#pragma unroll
    for (int c = 0; c < 4; ++c) {
        int kk = c * 256 + tid;
        if (kk < eff) {
            const float* Kr = Kbase + (size_t)kk * DIMS;
            float d0 = 0, d1 = 0, d2 = 0, d3 = 0;
#pragma unroll
            for (int j = 0; j < 64; j += 4) {
                float4 kv = *(const float4*)(Kr + j);
                float4 q0 = *(const float4*)&qs[0][j];
                float4 q1 = *(const float4*)&qs[1][j];
                float4 q2 = *(const float4*)&qs[2][j];
                float4 q3 = *(const float4*)&qs[3][j];
                d0 += kv.x * q0.x + kv.y * q0.y + kv.z * q0.z + kv.w * q0.w;
                d1 += kv.x * q1.x + kv.y * q1.y + kv.z * q1.z + kv.w * q1.w;
                d2 += kv.x * q2.x + kv.y * q2.y + kv.z * q2.z + kv.w * q2.w;
                d3 += kv.x * q3.x + kv.y * q3.y + kv.z * q3.z + kv.w * q3.w;
            }
            d0 *= scale; d1 *= scale; d2 *= scale; d3 *= scale;
            sc[0][kk] = d0; sc[1][kk] = d1; sc[2][kk] = d2; sc[3][kk] = d3;
            mymax[0] = fmaxf(mymax[0], d0); mymax[1] = fmaxf(mymax[1], d1);
            mymax[2] = fmaxf(mymax[2], d2); mymax[3] = fmaxf(mymax[3], d3);
        } else {
            sc[0][kk] = -1e30f; sc[1][kk] = -1e30f;
            sc[2][kk] = -1e30f; sc[3][kk] = -1e30f;
        }
    }
#pragma unroll
    for (int o = 32; o > 0; o >>= 1) {
#pragma unroll
        for (int r = 0; r < 4; ++r)
            mymax[r] = fmaxf(mymax[r], __shfl_xor(mymax[r], o, 64));
    }
    int wid = tid >> 6, lane = tid & 63;
    if (lane == 0) {
#pragma unroll
        for (int r = 0; r < 4; ++r) red[r][wid] = mymax[r];
    }
    __syncthreads();
    float rmax[4];
#pragma unroll
    for (int r = 0; r < 4; ++r)
        rmax[r] = fmaxf(fmaxf(red[r][0], red[r][1]), fmaxf(red[r][2], red[r][3]));
    __syncthreads();
    float mysum[4] = {0, 0, 0, 0};
#pragma unroll
    for (int c = 0; c < 4; ++c) {
        int kk = c * 256 + tid;
#pragma unroll
        for (int r = 0; r < 4; ++r) {
            float e = expf(sc[r][kk] - rmax[r]);
            sc[r][kk] = e;
            mysum[r] += e;
        }
    }
#pragma unroll
    for (int o = 32; o > 0; o >>= 1) {
#pragma unroll
        for (int r = 0; r < 4; ++r) mysum[r] += __shfl_xor(mysum[r], o, 64);
    }
    if (lane == 0) {
#pragma unroll
        for (int r = 0; r < 4; ++r) red[r][wid] = mysum[r];
    }
    __syncthreads();
    float rcp[4];
#pragma unroll
    for (int r = 0; r < 4; ++r)
        rcp[r] = 1.0f / (red[r][0] + red[r][1] + red[r][2] + red[r][3]);
    // PV: wave w handles key chunk, lane = head dim
    int w = wid, d = lane;
    const float* Vbase = V + (size_t)(b * S_LEN) * DIMS + h * HD + d;
    float a0 = 0, a1 = 0, a2 = 0, a3 = 0;
    int k0 = w * 256;
    int kend = LOCAL ? min(k0 + 256, eff) : (k0 + 256);
    for (int k = k0; k < kend; ++k) {
        float vv = Vbase[(size_t)k * DIMS];
        a0 += sc[0][k] * vv; a1 += sc[1][k] * vv;
        a2 += sc[2][k] * vv; a3 += sc[3][k] * vv;
    }
    pacc[w][0][d] = a0; pacc[w][1][d] = a1; pacc[w][2][d] = a2; pacc[w][3][d] = a3;
    __syncthreads();
    int r = wid;
    float o = (pacc[0][r][d] + pacc[1][r][d] + pacc[2][r][d] + pacc[3][r][d]) * rcp[r];
    int srow = s0 + r;
    if (LOCAL && srow >= eff) o = 0.0f;
    O[(size_t)(b * S_LEN + srow) * ldo + h * HD + d] = o;
}

// ---------------- span predictor ----------------
__global__ __launch_bounds__(256) void span1_kernel(
    const float* __restrict__ gout, const float* __restrict__ Wp,
    float* __restrict__ partials)
{
    int slice = blockIdx.x;   // 0..7 (128 rows each)
    int b = blockIdx.y;
    int t = threadIdx.x;
    float4 wp = *(const float4*)(Wp + t * 4);
    float acc = 0;
    int s0 = slice * 128;
    for (int s = s0; s < s0 + 128; ++s) {
        float4 g = *(const float4*)(gout + (size_t)(b * S_LEN + s) * 2048 + t * 4);
        acc += g.x * wp.x + g.y * wp.y + g.z * wp.z + g.w * wp.w;
    }
#pragma unroll
    for (int o = 32; o > 0; o >>= 1) acc += __shfl_down(acc, o, 64);
    __shared__ float r[4];
    int wid = t >> 6, lane = t & 63;
    if (lane == 0) r[wid] = acc;
    __syncthreads();
    if (t == 0) partials[b * 8 + slice] = r[0] + r[1] + r[2] + r[3];
}

__global__ void span2_kernel(const float* __restrict__ partials,
                             const float* __restrict__ bp,
                             float* __restrict__ spanbuf)
{
    if (threadIdx.x == 0 && blockIdx.x == 0) {
        float l0 = 0, l1 = 0;
        for (int i = 0; i < 8; ++i) { l0 += partials[i]; l1 += partials[8 + i]; }
        l0 = l0 * (1.0f / 1024.0f) + bp[0];
        l1 = l1 * (1.0f / 1024.0f) + bp[0];
        float s0 = 1.0f / (1.0f + expf(-l0));
        float s1 = 1.0f / (1.0f + expf(-l1));
        float sm = 0.5f * (s0 + s1);
        int sl = (int)floorf(1024.0f * sm);
        int eff = sl; if (eff > 1024) eff = 1024; if (eff < 1) eff = 1;
        float temp = 1.0f + 0.01f * (1.0f - sm);
        spanbuf[0] = (float)eff;
        spanbuf[1] = 0.35355339059327378f / temp;  // 64^-0.25 / temp
    }
}

extern "C" void kernel_launch(void* const* d_in, const int* in_sizes, int n_in,
                              void* d_out, int out_size, void* d_ws, size_t ws_size,
                              hipStream_t stream)
{
    (void)in_sizes; (void)n_in; (void)out_size; (void)ws_size;
    const float* x   = (const float*)d_in[0];
    const float* lag = (const float*)d_in[1];
    const float* lab = (const float*)d_in[2];
    const float* lbg = (const float*)d_in[3];
    const float* lbb = (const float*)d_in[4];
    const float* Wq  = (const float*)d_in[5];
    const float* bq  = (const float*)d_in[6];
    const float* Wk  = (const float*)d_in[7];
    const float* Wv  = (const float*)d_in[8];
    const float* bv  = (const float*)d_in[9];
    const float* Wc  = (const float*)d_in[10];
    const float* bc  = (const float*)d_in[11];
    const float* Wp  = (const float*)d_in[12];
    const float* bp  = (const float*)d_in[13];
    const float* Wo  = (const float*)d_in[14];
    const float* bo  = (const float*)d_in[15];
    float* out = (float*)d_out;
    float* ws  = (float*)d_ws;

    const size_t NM = (size_t)MROWS * DIMS;  // 2M floats
    float* lnA  = ws;            // local LN            [2048,1024]
    float* lnB  = ws + NM;       // globe LN -> g_att   [2048,1024]
    float* qb   = ws + 2 * NM;   // q                   [2048,1024]
    float* kb   = ws + 3 * NM;   // k                   [2048,1024]
    float* vb   = ws + 4 * NM;   // v                   [2048,1024]
    float* comb = ws + 2 * NM;   // [2048,2048] l_out | g_out (reuses q,k region)
    float* partials = ws + 5 * NM;       // 16 floats
    float* spanbuf  = ws + 5 * NM + 16;  // [eff, lscale]

    ln2_kernel<<<MROWS, 256, 0, stream>>>(x, lag, lab, lbg, lbb, lnA, lnB);

    dim3 gg(DIMS / 64, MROWS / 64);
    gemm_f32<<<gg, 256, 0, stream>>>(lnB, DIMS, Wq, DIMS, bq,      qb, DIMS, DIMS);
    gemm_f32<<<gg, 256, 0, stream>>>(lnB, DIMS, Wk, DIMS, nullptr, kb, DIMS, DIMS);
    gemm_f32<<<gg, 256, 0, stream>>>(lnB, DIMS, Wv, DIMS, bv,      vb, DIMS, DIMS);

    dim3 ag(S_LEN / 4, NHEAD, BATCH);
    attn_kernel<0><<<ag, 256, 0, stream>>>(qb, kb, vb, lnB, DIMS, nullptr);

    // g_out -> comb[:, 1024:2048]
    gemm_f32<<<gg, 256, 0, stream>>>(lnB, DIMS, Wc, DIMS, bc, comb + 1024, 2048, DIMS);

    span1_kernel<<<dim3(8, BATCH), 256, 0, stream>>>(comb + 1024, Wp, partials);
    span2_kernel<<<1, 64, 0, stream>>>(partials, bp, spanbuf);

    // l_out -> comb[:, 0:1024]
    attn_kernel<1><<<ag, 256, 0, stream>>>(lnA, lnA, lnA, comb, 2048, spanbuf);

    // out = comb @ Wo^T + bo   (K = 2048)
    gemm_f32<<<gg, 256, 0, stream>>>(comb, 2048, Wo, 2048, bo, out, DIMS, 2 * DIMS);
}

// Round 2
// 520.763 us; speedup vs baseline: 1.9430x; 1.9430x over previous
//
#include <hip/hip_runtime.h>
#include <math.h>

#define S_LEN 1024
#define DIMS  1024
#define NHEAD 16
#define HD    64
#define BATCH 2
#define MROWS (BATCH * S_LEN)   // 2048

typedef __attribute__((ext_vector_type(8))) __bf16 bf8_t;
typedef __attribute__((ext_vector_type(8))) unsigned short us8_t;
typedef __attribute__((ext_vector_type(4))) float f32x4;

static __device__ inline unsigned short f2bf(float f) {
    unsigned int u = __builtin_bit_cast(unsigned int, f);
    unsigned int r = u + 0x7fffu + ((u >> 16) & 1u);
    return (unsigned short)(r >> 16);
}

static __device__ inline f32x4 mfma16(us8_t a, us8_t b, f32x4 c) {
    return __builtin_amdgcn_mfma_f32_16x16x32_bf16(
        __builtin_bit_cast(bf8_t, a), __builtin_bit_cast(bf8_t, b), c, 0, 0, 0);
}

// ---------------- LayerNorm (both local & globe in one pass) ----------------
__global__ __launch_bounds__(256) void ln2_kernel(
    const float* __restrict__ x,
    const float* __restrict__ ga, const float* __restrict__ ba,
    const float* __restrict__ gb, const float* __restrict__ bb,
    float* __restrict__ outA, float* __restrict__ outB)
{
    int row = blockIdx.x;
    int t = threadIdx.x;
    const float* xr = x + (size_t)row * DIMS;
    float4 v = *(const float4*)(xr + t * 4);
    float s  = v.x + v.y + v.z + v.w;
    float s2 = v.x * v.x + v.y * v.y + v.z * v.z + v.w * v.w;
#pragma unroll
    for (int o = 32; o > 0; o >>= 1) {
        s  += __shfl_down(s, o, 64);
        s2 += __shfl_down(s2, o, 64);
    }
    __shared__ float rs[4], rs2[4];
    int wid = t >> 6, lane = t & 63;
    if (lane == 0) { rs[wid] = s; rs2[wid] = s2; }
    __syncthreads();
    float S0 = rs[0] + rs[1] + rs[2] + rs[3];
    float S2 = rs2[0] + rs2[1] + rs2[2] + rs2[3];
    float mean = S0 * (1.0f / DIMS);
    float var  = S2 * (1.0f / DIMS) - mean * mean;
    float inv  = 1.0f / sqrtf(var + 1e-5f);
    float4 vga = *(const float4*)(ga + t * 4);
    float4 vba = *(const float4*)(ba + t * 4);
    float4 vgb = *(const float4*)(gb + t * 4);
    float4 vbb = *(const float4*)(bb + t * 4);
    float nx = (v.x - mean) * inv, ny = (v.y - mean) * inv;
    float nz = (v.z - mean) * inv, nw = (v.w - mean) * inv;
    float4 oa = make_float4(nx * vga.x + vba.x, ny * vga.y + vba.y,
                            nz * vga.z + vba.z, nw * vga.w + vba.w);
    float4 ob = make_float4(nx * vgb.x + vbb.x, ny * vgb.y + vbb.y,
                            nz * vgb.z + vbb.z, nw * vgb.w + vbb.w);
    *(float4*)(outA + (size_t)row * DIMS + t * 4) = oa;
    *(float4*)(outB + (size_t)row * DIMS + t * 4) = ob;
}

// ---------------- f32 GEMM: C[M,N] = A[M,K] @ W[N,K]^T (+bias) --------------
__global__ __launch_bounds__(256) void gemm_f32(
    const float* __restrict__ A, int lda,
    const float* __restrict__ W, int ldw,
    const float* __restrict__ bias,
    float* __restrict__ C, int ldc,
    int K)
{
    __shared__ float As[16][68];
    __shared__ float Bs[16][68];
    int tid = threadIdx.x;
    int bm = blockIdx.y * 64, bn = blockIdx.x * 64;
    int tx = tid & 15, ty = tid >> 4;
    int lrow = tid >> 2;
    int lk   = (tid & 3) * 4;
    float acc[4][4] = {{0.f,0.f,0.f,0.f},{0.f,0.f,0.f,0.f},{0.f,0.f,0.f,0.f},{0.f,0.f,0.f,0.f}};
    const float* Aptr = A + (size_t)(bm + lrow) * lda + lk;
    const float* Wptr = W + (size_t)(bn + lrow) * ldw + lk;
    for (int kk = 0; kk < K; kk += 16) {
        float4 a = *(const float4*)(Aptr + kk);
        float4 b = *(const float4*)(Wptr + kk);
        __syncthreads();
        As[lk + 0][lrow] = a.x; As[lk + 1][lrow] = a.y;
        As[lk + 2][lrow] = a.z; As[lk + 3][lrow] = a.w;
        Bs[lk + 0][lrow] = b.x; Bs[lk + 1][lrow] = b.y;
        Bs[lk + 2][lrow] = b.z; Bs[lk + 3][lrow] = b.w;
        __syncthreads();
#pragma unroll
        for (int k = 0; k < 16; ++k) {
            float4 av = *(const float4*)&As[k][ty * 4];
            float4 bv = *(const float4*)&Bs[k][tx * 4];
            float ar[4] = {av.x, av.y, av.z, av.w};
            float br[4] = {bv.x, bv.y, bv.z, bv.w};
#pragma unroll
            for (int i = 0; i < 4; ++i)
#pragma unroll
                for (int j = 0; j < 4; ++j)
                    acc[i][j] += ar[i] * br[j];
        }
    }
    float4 bfrag = make_float4(0.f, 0.f, 0.f, 0.f);
    if (bias) bfrag = *(const float4*)(bias + bn + tx * 4);
#pragma unroll
    for (int i = 0; i < 4; ++i) {
        float4 o = make_float4(acc[i][0] + bfrag.x, acc[i][1] + bfrag.y,
                               acc[i][2] + bfrag.z, acc[i][3] + bfrag.w);
        *(float4*)(C + (size_t)(bm + ty * 4 + i) * ldc + bn + tx * 4) = o;
    }
}

// ---------------- MFMA flash attention ----------------
// Block: 4 waves, 64 q-rows, one (b,h). Loop over 64-key tiles.
// f32 inputs converted to bf16 during LDS staging.
// Fragment conventions (m91-verified):
//   A-frag: lane l holds A[row = l&15][k = (l>>4)*8 + j]  (8 bf16, 16B)
//   B-frag: lane l holds B'[row = l&15][k = (l>>4)*8 + j] where B' is [N,K]
//   C/D   : lane l, reg r hold D[row = (l>>4)*4 + r][col = l&15]
// LDS tiles are [row][64] bf16 (128B rows, 8 x 16B slots), slot ^= (row&7).
template <int LOCAL>
__global__ __launch_bounds__(256) void attn_mfma(
    const float* __restrict__ Q, const float* __restrict__ K,
    const float* __restrict__ V, float* __restrict__ O, int ldo,
    const float* __restrict__ span)
{
    __shared__ __align__(16) unsigned short Ks[64 * 64];   // [key][d] swizzled
    __shared__ __align__(16) unsigned short Vt[64 * 64];   // [d][key] swizzled
    __shared__ __align__(16) unsigned short Ps[4][16 * 64];// per-wave [q][key] swizzled

    int b = blockIdx.z, h = blockIdx.y;
    int q0blk = blockIdx.x * 64;
    int tid = threadIdx.x;
    int w = tid >> 6, l = tid & 63;
    int l15 = l & 15, lhi = l >> 4;

    float scale; int eff;
    if (LOCAL) { scale = span[1]; eff = (int)span[0]; }
    else       { scale = 1.0f / 64.0f; eff = S_LEN; }
    int ntiles = LOCAL ? ((eff + 63) >> 6) : 16;

    // Q fragments in registers: rows q0blk + w*16 + (l&15)
    int qrow = q0blk + w * 16 + l15;
    const float* qptr = Q + ((size_t)(b * S_LEN + qrow)) * DIMS + h * HD + lhi * 8;
    us8_t qf[2];
#pragma unroll
    for (int kk = 0; kk < 2; ++kk) {
        float4 x0 = *(const float4*)(qptr + kk * 32);
        float4 x1 = *(const float4*)(qptr + kk * 32 + 4);
        us8_t f;
        f[0] = f2bf(x0.x); f[1] = f2bf(x0.y); f[2] = f2bf(x0.z); f[3] = f2bf(x0.w);
        f[4] = f2bf(x1.x); f[5] = f2bf(x1.y); f[6] = f2bf(x1.z); f[7] = f2bf(x1.w);
        qf[kk] = f;
    }

    f32x4 o[4] = {{0,0,0,0},{0,0,0,0},{0,0,0,0},{0,0,0,0}};
    float m_r[4] = {-1e30f, -1e30f, -1e30f, -1e30f};
    float l_r[4] = {0.f, 0.f, 0.f, 0.f};

    for (int kt = 0; kt < ntiles; ++kt) {
        __syncthreads();  // prior tile's LDS reads done
        // ---- stage K tile [64 key][64 d] ----
        {
            int key = tid >> 2, dc = (tid & 3) * 16;
            const float* kp = K + ((size_t)(b * S_LEN + kt * 64 + key)) * DIMS + h * HD + dc;
            float4 a = *(const float4*)(kp + 0);
            float4 c = *(const float4*)(kp + 4);
            float4 d2 = *(const float4*)(kp + 8);
            float4 e = *(const float4*)(kp + 12);
            us8_t c0, c1;
            c0[0]=f2bf(a.x); c0[1]=f2bf(a.y); c0[2]=f2bf(a.z); c0[3]=f2bf(a.w);
            c0[4]=f2bf(c.x); c0[5]=f2bf(c.y); c0[6]=f2bf(c.z); c0[7]=f2bf(c.w);
            c1[0]=f2bf(d2.x); c1[1]=f2bf(d2.y); c1[2]=f2bf(d2.z); c1[3]=f2bf(d2.w);
            c1[4]=f2bf(e.x); c1[5]=f2bf(e.y); c1[6]=f2bf(e.z); c1[7]=f2bf(e.w);
            int s0 = ((dc >> 3) + 0) ^ (key & 7);
            int s1 = ((dc >> 3) + 1) ^ (key & 7);
            *(us8_t*)&Ks[key * 64 + s0 * 8] = c0;
            *(us8_t*)&Ks[key * 64 + s1 * 8] = c1;
        }
        // ---- stage V tile transposed -> Vt[64 d][64 key] ----
        {
            int key = tid & 63, db = (tid >> 6) * 16;
            const float* vp = V + ((size_t)(b * S_LEN + kt * 64 + key)) * DIMS + h * HD + db;
            float4 a = *(const float4*)(vp + 0);
            float4 c = *(const float4*)(vp + 4);
            float4 d2 = *(const float4*)(vp + 8);
            float4 e = *(const float4*)(vp + 12);
            float f[16] = {a.x,a.y,a.z,a.w, c.x,c.y,c.z,c.w,
                           d2.x,d2.y,d2.z,d2.w, e.x,e.y,e.z,e.w};
#pragma unroll
            for (int j = 0; j < 16; ++j) {
                int d = db + j;
                int slot = (key >> 3) ^ (d & 7);
                Vt[d * 64 + slot * 8 + (key & 7)] = f2bf(f[j]);
            }
        }
        __syncthreads();  // tiles staged

        // ---- S = Q @ K^T  (per wave: 16 q rows x 64 keys) ----
        f32x4 s4[4] = {{0,0,0,0},{0,0,0,0},{0,0,0,0},{0,0,0,0}};
#pragma unroll
        for (int kk = 0; kk < 2; ++kk) {
#pragma unroll
            for (int n = 0; n < 4; ++n) {
                int key = n * 16 + l15;
                int slot = (kk * 4 + lhi) ^ (key & 7);
                us8_t bk = *(const us8_t*)&Ks[key * 64 + slot * 8];
                s4[n] = mfma16(qf[kk], bk, s4[n]);
            }
        }
        // scale + mask
#pragma unroll
        for (int n = 0; n < 4; ++n) {
            s4[n] *= scale;
            if (LOCAL) {
                int key = kt * 64 + n * 16 + l15;
                if (key >= eff) { s4[n][0] = -1e30f; s4[n][1] = -1e30f; s4[n][2] = -1e30f; s4[n][3] = -1e30f; }
            }
        }
        // ---- online softmax ----
        float tm[4];
#pragma unroll
        for (int r = 0; r < 4; ++r)
            tm[r] = fmaxf(fmaxf(s4[0][r], s4[1][r]), fmaxf(s4[2][r], s4[3][r]));
#pragma unroll
        for (int msk = 1; msk <= 8; msk <<= 1) {
#pragma unroll
            for (int r = 0; r < 4; ++r)
                tm[r] = fmaxf(tm[r], __shfl_xor(tm[r], msk, 64));
        }
        float fac[4];
#pragma unroll
        for (int r = 0; r < 4; ++r) {
            float mn = fmaxf(m_r[r], tm[r]);
            fac[r] = expf(m_r[r] - mn);
            m_r[r] = mn;
            l_r[r] *= fac[r];
        }
#pragma unroll
        for (int n = 0; n < 4; ++n) {
            o[n][0] *= fac[0]; o[n][1] *= fac[1]; o[n][2] *= fac[2]; o[n][3] *= fac[3];
        }
        float ladd[4] = {0.f, 0.f, 0.f, 0.f};
#pragma unroll
        for (int n = 0; n < 4; ++n) {
            int col = n * 16 + l15;
            int slotbase = col >> 3;
#pragma unroll
            for (int r = 0; r < 4; ++r) {
                float p = expf(s4[n][r] - m_r[r]);
                ladd[r] += p;
                int qlr = lhi * 4 + r;
                int slot = slotbase ^ (qlr & 7);
                Ps[w][qlr * 64 + slot * 8 + (col & 7)] = f2bf(p);
            }
        }
#pragma unroll
        for (int msk = 1; msk <= 8; msk <<= 1) {
#pragma unroll
            for (int r = 0; r < 4; ++r)
                ladd[r] += __shfl_xor(ladd[r], msk, 64);
        }
#pragma unroll
        for (int r = 0; r < 4; ++r) l_r[r] += ladd[r];

        __syncthreads();  // P visible (also orders Ks/Vt reuse)

        // ---- O += P @ V ----
#pragma unroll
        for (int kk = 0; kk < 2; ++kk) {
            int slot = (kk * 4 + lhi) ^ (l15 & 7);
            us8_t pa = *(const us8_t*)&Ps[w][l15 * 64 + slot * 8];
#pragma unroll
            for (int n = 0; n < 4; ++n) {
                int d = n * 16 + l15;
                int vslot = (kk * 4 + lhi) ^ (d & 7);
                us8_t vb = *(const us8_t*)&Vt[d * 64 + vslot * 8];
                o[n] = mfma16(pa, vb, o[n]);
            }
        }
    }

    // ---- finalize ----
    float rcp[4];
#pragma unroll
    for (int r = 0; r < 4; ++r) rcp[r] = 1.0f / l_r[r];
#pragma unroll
    for (int n = 0; n < 4; ++n) {
#pragma unroll
        for (int r = 0; r < 4; ++r) {
            int row = q0blk + w * 16 + lhi * 4 + r;
            float val = o[n][r] * rcp[r];
            if (LOCAL && row >= eff) val = 0.0f;
            O[((size_t)(b * S_LEN + row)) * ldo + h * HD + n * 16 + l15] = val;
        }
    }
}

// ---------------- span predictor ----------------
__global__ __launch_bounds__(256) void span1_kernel(
    const float* __restrict__ gout, const float* __restrict__ Wp,
    float* __restrict__ partials)
{
    int slice = blockIdx.x;   // 0..7 (128 rows each)
    int b = blockIdx.y;
    int t = threadIdx.x;
    float4 wp = *(const float4*)(Wp + t * 4);
    float acc = 0;
    int s0 = slice * 128;
    for (int s = s0; s < s0 + 128; ++s) {
        float4 g = *(const float4*)(gout + (size_t)(b * S_LEN + s) * 2048 + t * 4);
        acc += g.x * wp.x + g.y * wp.y + g.z * wp.z + g.w * wp.w;
    }
#pragma unroll
    for (int o = 32; o > 0; o >>= 1) acc += __shfl_down(acc, o, 64);
    __shared__ float r[4];
    int wid = t >> 6, lane = t & 63;
    if (lane == 0) r[wid] = acc;
    __syncthreads();
    if (t == 0) partials[b * 8 + slice] = r[0] + r[1] + r[2] + r[3];
}

__global__ void span2_kernel(const float* __restrict__ partials,
                             const float* __restrict__ bp,
                             float* __restrict__ spanbuf)
{
    if (threadIdx.x == 0 && blockIdx.x == 0) {
        float l0 = 0, l1 = 0;
        for (int i = 0; i < 8; ++i) { l0 += partials[i]; l1 += partials[8 + i]; }
        l0 = l0 * (1.0f / 1024.0f) + bp[0];
        l1 = l1 * (1.0f / 1024.0f) + bp[0];
        float s0 = 1.0f / (1.0f + expf(-l0));
        float s1 = 1.0f / (1.0f + expf(-l1));
        float sm = 0.5f * (s0 + s1);
        int sl = (int)floorf(1024.0f * sm);
        int eff = sl; if (eff > 1024) eff = 1024; if (eff < 1) eff = 1;
        float temp = 1.0f + 0.01f * (1.0f - sm);
        spanbuf[0] = (float)eff;
        spanbuf[1] = 0.35355339059327378f / temp;  // 64^-0.25 / temp
    }
}

extern "C" void kernel_launch(void* const* d_in, const int* in_sizes, int n_in,
                              void* d_out, int out_size, void* d_ws, size_t ws_size,
                              hipStream_t stream)
{
    (void)in_sizes; (void)n_in; (void)out_size; (void)ws_size;
    const float* x   = (const float*)d_in[0];
    const float* lag = (const float*)d_in[1];
    const float* lab = (const float*)d_in[2];
    const float* lbg = (const float*)d_in[3];
    const float* lbb = (const float*)d_in[4];
    const float* Wq  = (const float*)d_in[5];
    const float* bq  = (const float*)d_in[6];
    const float* Wk  = (const float*)d_in[7];
    const float* Wv  = (const float*)d_in[8];
    const float* bv  = (const float*)d_in[9];
    const float* Wc  = (const float*)d_in[10];
    const float* bc  = (const float*)d_in[11];
    const float* Wp  = (const float*)d_in[12];
    const float* bp  = (const float*)d_in[13];
    const float* Wo  = (const float*)d_in[14];
    const float* bo  = (const float*)d_in[15];
    float* out = (float*)d_out;
    float* ws  = (float*)d_ws;

    const size_t NM = (size_t)MROWS * DIMS;  // 2M floats
    float* lnA  = ws;            // local LN            [2048,1024]
    float* lnB  = ws + NM;       // globe LN -> g_att   [2048,1024]
    float* qb   = ws + 2 * NM;   // q                   [2048,1024]
    float* kb   = ws + 3 * NM;   // k                   [2048,1024]
    float* vb   = ws + 4 * NM;   // v                   [2048,1024]
    float* comb = ws + 2 * NM;   // [2048,2048] l_out | g_out (reuses q,k region)
    float* partials = ws + 5 * NM;       // 16 floats
    float* spanbuf  = ws + 5 * NM + 16;  // [eff, lscale]

    ln2_kernel<<<MROWS, 256, 0, stream>>>(x, lag, lab, lbg, lbb, lnA, lnB);

    dim3 gg(DIMS / 64, MROWS / 64);
    gemm_f32<<<gg, 256, 0, stream>>>(lnB, DIMS, Wq, DIMS, bq,      qb, DIMS, DIMS);
    gemm_f32<<<gg, 256, 0, stream>>>(lnB, DIMS, Wk, DIMS, nullptr, kb, DIMS, DIMS);
    gemm_f32<<<gg, 256, 0, stream>>>(lnB, DIMS, Wv, DIMS, bv,      vb, DIMS, DIMS);

    dim3 ag(S_LEN / 64, NHEAD, BATCH);
    attn_mfma<0><<<ag, 256, 0, stream>>>(qb, kb, vb, lnB, DIMS, nullptr);

    // g_out -> comb[:, 1024:2048]
    gemm_f32<<<gg, 256, 0, stream>>>(lnB, DIMS, Wc, DIMS, bc, comb + 1024, 2048, DIMS);

    span1_kernel<<<dim3(8, BATCH), 256, 0, stream>>>(comb + 1024, Wp, partials);
    span2_kernel<<<1, 64, 0, stream>>>(partials, bp, spanbuf);

    // l_out -> comb[:, 0:1024]
    attn_mfma<1><<<ag, 256, 0, stream>>>(lnA, lnA, lnA, comb, 2048, spanbuf);

    // out = comb @ Wo^T + bo   (K = 2048)
    gemm_f32<<<gg, 256, 0, stream>>>(comb, 2048, Wo, 2048, bo, out, DIMS, 2 * DIMS);
}

// Round 3
// 176.909 us; speedup vs baseline: 5.7196x; 2.9437x over previous
//
#include <hip/hip_runtime.h>
#include <math.h>

#define S_LEN 1024
#define DIMS  1024
#define NHEAD 16
#define HD    64
#define BATCH 2
#define MROWS (BATCH * S_LEN)   // 2048

typedef unsigned short us;
typedef __attribute__((ext_vector_type(8))) __bf16 bf8_t;
typedef __attribute__((ext_vector_type(8))) unsigned short us8_t;
typedef __attribute__((ext_vector_type(4))) unsigned short us4_t;
typedef __attribute__((ext_vector_type(4))) float f32x4;

static __device__ inline us f2bf(float f) {
    unsigned int u = __builtin_bit_cast(unsigned int, f);
    unsigned int r = u + 0x7fffu + ((u >> 16) & 1u);
    return (us)(r >> 16);
}
static __device__ inline float bf2f(us v) {
    unsigned int u = ((unsigned int)v) << 16;
    return __builtin_bit_cast(float, u);
}
static __device__ inline f32x4 mfma16(us8_t a, us8_t b, f32x4 c) {
    return __builtin_amdgcn_mfma_f32_16x16x32_bf16(
        __builtin_bit_cast(bf8_t, a), __builtin_bit_cast(bf8_t, b), c, 0, 0, 0);
}

// ---------------- f32 -> bf16 convert ----------------
__global__ __launch_bounds__(256) void cvt_kernel(const float* __restrict__ src,
                                                  us* __restrict__ dst)
{
    int idx = blockIdx.x * 1024 + threadIdx.x * 4;
    float4 v = *(const float4*)(src + idx);
    us4_t o;
    o[0] = f2bf(v.x); o[1] = f2bf(v.y); o[2] = f2bf(v.z); o[3] = f2bf(v.w);
    *(us4_t*)(dst + idx) = o;
}

// ---------------- LayerNorm (both, bf16 out) ----------------
__global__ __launch_bounds__(256) void ln2_kernel(
    const float* __restrict__ x,
    const float* __restrict__ ga, const float* __restrict__ ba,
    const float* __restrict__ gb, const float* __restrict__ bb,
    us* __restrict__ outA, us* __restrict__ outB)
{
    int row = blockIdx.x;
    int t = threadIdx.x;
    const float* xr = x + (size_t)row * DIMS;
    float4 v = *(const float4*)(xr + t * 4);
    float s  = v.x + v.y + v.z + v.w;
    float s2 = v.x * v.x + v.y * v.y + v.z * v.z + v.w * v.w;
#pragma unroll
    for (int o = 32; o > 0; o >>= 1) {
        s  += __shfl_down(s, o, 64);
        s2 += __shfl_down(s2, o, 64);
    }
    __shared__ float rs[4], rs2[4];
    int wid = t >> 6, lane = t & 63;
    if (lane == 0) { rs[wid] = s; rs2[wid] = s2; }
    __syncthreads();
    float S0 = rs[0] + rs[1] + rs[2] + rs[3];
    float S2 = rs2[0] + rs2[1] + rs2[2] + rs2[3];
    float mean = S0 * (1.0f / DIMS);
    float var  = S2 * (1.0f / DIMS) - mean * mean;
    float inv  = 1.0f / sqrtf(var + 1e-5f);
    float4 vga = *(const float4*)(ga + t * 4);
    float4 vba = *(const float4*)(ba + t * 4);
    float4 vgb = *(const float4*)(gb + t * 4);
    float4 vbb = *(const float4*)(bb + t * 4);
    float nx = (v.x - mean) * inv, ny = (v.y - mean) * inv;
    float nz = (v.z - mean) * inv, nw = (v.w - mean) * inv;
    us4_t oa, ob;
    oa[0] = f2bf(nx * vga.x + vba.x); oa[1] = f2bf(ny * vga.y + vba.y);
    oa[2] = f2bf(nz * vga.z + vba.z); oa[3] = f2bf(nw * vga.w + vba.w);
    ob[0] = f2bf(nx * vgb.x + vbb.x); ob[1] = f2bf(ny * vgb.y + vbb.y);
    ob[2] = f2bf(nz * vgb.z + vbb.z); ob[3] = f2bf(nw * vgb.w + vbb.w);
    *(us4_t*)(outA + (size_t)row * DIMS + t * 4) = oa;
    *(us4_t*)(outB + (size_t)row * DIMS + t * 4) = ob;
}

// ---------------- bf16 MFMA GEMM: C[M,N] = A[M,K] @ W[N,K]^T (+bias) -------
// 64x64 tile, 4 waves (2x2), each wave 32x32. XOR slot-swizzled LDS.
// OUTBF: 1 -> bf16 output, 0 -> f32 output
template <int OUTBF>
__global__ __launch_bounds__(256) void gemm_bf16(
    const us* __restrict__ A, int lda,
    const us* __restrict__ W, int ldw,
    const float* __restrict__ bias,
    void* __restrict__ Cp, int ldc, int K)
{
    __shared__ __align__(16) us As[64 * 64];
    __shared__ __align__(16) us Bs[64 * 64];
    int tid = threadIdx.x;
    int w = tid >> 6, l = tid & 63, l15 = l & 15, lhi = l >> 4;
    int wr = w >> 1, wc = w & 1;
    int bm = blockIdx.y * 64, bn = blockIdx.x * 64;
    f32x4 acc[2][2] = {{{0,0,0,0},{0,0,0,0}},{{0,0,0,0},{0,0,0,0}}};
    int srow = tid >> 3;            // 0..31
    int scol8 = tid & 7;            // 16B slot within row
    const us* Ap = A + (size_t)(bm + srow) * lda + scol8 * 8;
    const us* Wpt = W + (size_t)(bn + srow) * ldw + scol8 * 8;
    int sl = (scol8 ^ (srow & 7)) * 8;
    for (int kt = 0; kt < K; kt += 64) {
        us8_t a0 = *(const us8_t*)(Ap + kt);
        us8_t a1 = *(const us8_t*)(Ap + (size_t)32 * lda + kt);
        us8_t b0 = *(const us8_t*)(Wpt + kt);
        us8_t b1 = *(const us8_t*)(Wpt + (size_t)32 * ldw + kt);
        __syncthreads();
        *(us8_t*)&As[srow * 64 + sl] = a0;
        *(us8_t*)&As[(srow + 32) * 64 + sl] = a1;
        *(us8_t*)&Bs[srow * 64 + sl] = b0;
        *(us8_t*)&Bs[(srow + 32) * 64 + sl] = b1;
        __syncthreads();
#pragma unroll
        for (int kk = 0; kk < 2; ++kk) {
            us8_t af[2], bfr[2];
#pragma unroll
            for (int m = 0; m < 2; ++m) {
                int rowm = wr * 32 + m * 16 + l15;
                af[m] = *(const us8_t*)&As[rowm * 64 + (((kk * 4 + lhi)) ^ (rowm & 7)) * 8];
            }
#pragma unroll
            for (int n = 0; n < 2; ++n) {
                int rown = wc * 32 + n * 16 + l15;
                bfr[n] = *(const us8_t*)&Bs[rown * 64 + (((kk * 4 + lhi)) ^ (rown & 7)) * 8];
            }
#pragma unroll
            for (int m = 0; m < 2; ++m)
#pragma unroll
                for (int n = 0; n < 2; ++n)
                    acc[m][n] = mfma16(af[m], bfr[n], acc[m][n]);
        }
    }
    float bvv[2] = {0.f, 0.f};
    if (bias) {
#pragma unroll
        for (int n = 0; n < 2; ++n)
            bvv[n] = bias[bn + wc * 32 + n * 16 + l15];
    }
#pragma unroll
    for (int m = 0; m < 2; ++m) {
#pragma unroll
        for (int n = 0; n < 2; ++n) {
#pragma unroll
            for (int r = 0; r < 4; ++r) {
                int row = bm + wr * 32 + m * 16 + lhi * 4 + r;
                int col = bn + wc * 32 + n * 16 + l15;
                float val = acc[m][n][r] + bvv[n];
                if (OUTBF) ((us*)Cp)[(size_t)row * ldc + col] = f2bf(val);
                else       ((float*)Cp)[(size_t)row * ldc + col] = val;
            }
        }
    }
}

// ---------------- MFMA flash attention (bf16 in, bf16 out) ----------------
// Block: 4 waves, 64 q-rows, one (b,h). Loop over 64-key tiles.
template <int LOCAL>
__global__ __launch_bounds__(256) void attn_mfma(
    const us* __restrict__ Q, const us* __restrict__ K,
    const us* __restrict__ V, us* __restrict__ O, int ldo,
    const float* __restrict__ span)
{
    __shared__ __align__(16) us Ks[64 * 64];   // [key][d] swizzled
    __shared__ __align__(16) us Vt[64 * 64];   // [d][key] swizzled
    __shared__ __align__(16) us Ps[4][16 * 64];// per-wave [q][key] swizzled

    int b = blockIdx.z, h = blockIdx.y;
    int q0blk = blockIdx.x * 64;
    int tid = threadIdx.x;
    int w = tid >> 6, l = tid & 63;
    int l15 = l & 15, lhi = l >> 4;

    float scale; int eff;
    if (LOCAL) { scale = span[1]; eff = (int)span[0]; }
    else       { scale = 1.0f / 64.0f; eff = S_LEN; }
    int ntiles = LOCAL ? ((eff + 63) >> 6) : 16;

    int qrow = q0blk + w * 16 + l15;
    const us* qptr = Q + ((size_t)(b * S_LEN + qrow)) * DIMS + h * HD + lhi * 8;
    us8_t qf[2];
    qf[0] = *(const us8_t*)(qptr);
    qf[1] = *(const us8_t*)(qptr + 32);

    f32x4 o[4] = {{0,0,0,0},{0,0,0,0},{0,0,0,0},{0,0,0,0}};
    float m_r[4] = {-1e30f, -1e30f, -1e30f, -1e30f};
    float l_r[4] = {0.f, 0.f, 0.f, 0.f};

    // staging coords
    int krow = tid >> 3, kcol8 = tid & 7;                  // K tile
    int ksl = (kcol8 ^ (krow & 7)) * 8;
    int vkb = tid & 15, vdb = tid >> 4;                    // V 4x4 transpose block

    for (int kt = 0; kt < ntiles; ++kt) {
        __syncthreads();
        // ---- stage K tile [64 key][64 d], us8 x2 ----
        {
            const us* kp = K + ((size_t)(b * S_LEN + kt * 64 + krow)) * DIMS + h * HD + kcol8 * 8;
            us8_t c0 = *(const us8_t*)(kp);
            us8_t c1 = *(const us8_t*)(kp + (size_t)32 * DIMS);
            *(us8_t*)&Ks[krow * 64 + ksl] = c0;
            *(us8_t*)&Ks[(krow + 32) * 64 + ksl] = c1;
        }
        // ---- stage V tile transposed via 4x4 in-register transpose ----
        {
            const us* vp = V + ((size_t)(b * S_LEN + kt * 64 + vkb * 4)) * DIMS + h * HD + vdb * 4;
            us4_t r0 = *(const us4_t*)(vp);
            us4_t r1 = *(const us4_t*)(vp + DIMS);
            us4_t r2 = *(const us4_t*)(vp + 2 * DIMS);
            us4_t r3 = *(const us4_t*)(vp + 3 * DIMS);
#pragma unroll
            for (int j = 0; j < 4; ++j) {
                int d = vdb * 4 + j;
                us4_t wv;
                wv[0] = r0[j]; wv[1] = r1[j]; wv[2] = r2[j]; wv[3] = r3[j];
                int slot = (vkb >> 1) ^ (d & 7);
                *(us4_t*)&Vt[d * 64 + slot * 8 + (vkb & 1) * 4] = wv;
            }
        }
        __syncthreads();

        // ---- S = Q @ K^T ----
        f32x4 s4[4] = {{0,0,0,0},{0,0,0,0},{0,0,0,0},{0,0,0,0}};
#pragma unroll
        for (int kk = 0; kk < 2; ++kk) {
#pragma unroll
            for (int n = 0; n < 4; ++n) {
                int key = n * 16 + l15;
                int slot = (kk * 4 + lhi) ^ (key & 7);
                us8_t bk = *(const us8_t*)&Ks[key * 64 + slot * 8];
                s4[n] = mfma16(qf[kk], bk, s4[n]);
            }
        }
#pragma unroll
        for (int n = 0; n < 4; ++n) {
            s4[n] *= scale;
            if (LOCAL) {
                int key = kt * 64 + n * 16 + l15;
                if (key >= eff) { s4[n][0] = -1e30f; s4[n][1] = -1e30f; s4[n][2] = -1e30f; s4[n][3] = -1e30f; }
            }
        }
        // ---- online softmax ----
        float tm[4];
#pragma unroll
        for (int r = 0; r < 4; ++r)
            tm[r] = fmaxf(fmaxf(s4[0][r], s4[1][r]), fmaxf(s4[2][r], s4[3][r]));
#pragma unroll
        for (int msk = 1; msk <= 8; msk <<= 1) {
#pragma unroll
            for (int r = 0; r < 4; ++r)
                tm[r] = fmaxf(tm[r], __shfl_xor(tm[r], msk, 64));
        }
        float fac[4];
#pragma unroll
        for (int r = 0; r < 4; ++r) {
            float mn = fmaxf(m_r[r], tm[r]);
            fac[r] = __expf(m_r[r] - mn);
            m_r[r] = mn;
            l_r[r] *= fac[r];
        }
#pragma unroll
        for (int n = 0; n < 4; ++n) {
            o[n][0] *= fac[0]; o[n][1] *= fac[1]; o[n][2] *= fac[2]; o[n][3] *= fac[3];
        }
        float ladd[4] = {0.f, 0.f, 0.f, 0.f};
#pragma unroll
        for (int n = 0; n < 4; ++n) {
            int col = n * 16 + l15;
            int slotbase = col >> 3;
#pragma unroll
            for (int r = 0; r < 4; ++r) {
                float p = __expf(s4[n][r] - m_r[r]);
                ladd[r] += p;
                int qlr = lhi * 4 + r;
                int slot = slotbase ^ (qlr & 7);
                Ps[w][qlr * 64 + slot * 8 + (col & 7)] = f2bf(p);
            }
        }
#pragma unroll
        for (int msk = 1; msk <= 8; msk <<= 1) {
#pragma unroll
            for (int r = 0; r < 4; ++r)
                ladd[r] += __shfl_xor(ladd[r], msk, 64);
        }
#pragma unroll
        for (int r = 0; r < 4; ++r) l_r[r] += ladd[r];

        __syncthreads();

        // ---- O += P @ V ----
#pragma unroll
        for (int kk = 0; kk < 2; ++kk) {
            int slot = (kk * 4 + lhi) ^ (l15 & 7);
            us8_t pa = *(const us8_t*)&Ps[w][l15 * 64 + slot * 8];
#pragma unroll
            for (int n = 0; n < 4; ++n) {
                int d = n * 16 + l15;
                int vslot = (kk * 4 + lhi) ^ (d & 7);
                us8_t vb = *(const us8_t*)&Vt[d * 64 + vslot * 8];
                o[n] = mfma16(pa, vb, o[n]);
            }
        }
    }

    float rcp[4];
#pragma unroll
    for (int r = 0; r < 4; ++r) rcp[r] = 1.0f / l_r[r];
#pragma unroll
    for (int n = 0; n < 4; ++n) {
#pragma unroll
        for (int r = 0; r < 4; ++r) {
            int row = q0blk + w * 16 + lhi * 4 + r;
            float val = o[n][r] * rcp[r];
            if (LOCAL && row >= eff) val = 0.0f;
            O[((size_t)(b * S_LEN + row)) * ldo + h * HD + n * 16 + l15] = f2bf(val);
        }
    }
}

// ---------------- span predictor ----------------
__global__ __launch_bounds__(256) void span1_kernel(
    const us* __restrict__ gout, const float* __restrict__ Wp,
    float* __restrict__ partials)
{
    int slice = blockIdx.x;   // 0..7 (128 rows each)
    int b = blockIdx.y;
    int t = threadIdx.x;
    float4 wp = *(const float4*)(Wp + t * 4);
    float acc = 0;
    int s0 = slice * 128;
    for (int s = s0; s < s0 + 128; ++s) {
        us4_t g = *(const us4_t*)(gout + (size_t)(b * S_LEN + s) * 2048 + t * 4);
        acc += bf2f(g[0]) * wp.x + bf2f(g[1]) * wp.y + bf2f(g[2]) * wp.z + bf2f(g[3]) * wp.w;
    }
#pragma unroll
    for (int o = 32; o > 0; o >>= 1) acc += __shfl_down(acc, o, 64);
    __shared__ float r[4];
    int wid = t >> 6, lane = t & 63;
    if (lane == 0) r[wid] = acc;
    __syncthreads();
    if (t == 0) partials[b * 8 + slice] = r[0] + r[1] + r[2] + r[3];
}

__global__ void span2_kernel(const float* __restrict__ partials,
                             const float* __restrict__ bp,
                             float* __restrict__ spanbuf)
{
    if (threadIdx.x == 0 && blockIdx.x == 0) {
        float l0 = 0, l1 = 0;
        for (int i = 0; i < 8; ++i) { l0 += partials[i]; l1 += partials[8 + i]; }
        l0 = l0 * (1.0f / 1024.0f) + bp[0];
        l1 = l1 * (1.0f / 1024.0f) + bp[0];
        float s0 = 1.0f / (1.0f + expf(-l0));
        float s1 = 1.0f / (1.0f + expf(-l1));
        float sm = 0.5f * (s0 + s1);
        int sl = (int)floorf(1024.0f * sm);
        int eff = sl; if (eff > 1024) eff = 1024; if (eff < 1) eff = 1;
        float temp = 1.0f + 0.01f * (1.0f - sm);
        spanbuf[0] = (float)eff;
        spanbuf[1] = 0.35355339059327378f / temp;  // 64^-0.25 / temp
    }
}

extern "C" void kernel_launch(void* const* d_in, const int* in_sizes, int n_in,
                              void* d_out, int out_size, void* d_ws, size_t ws_size,
                              hipStream_t stream)
{
    (void)in_sizes; (void)n_in; (void)out_size; (void)ws_size;
    const float* x   = (const float*)d_in[0];
    const float* lag = (const float*)d_in[1];
    const float* lab = (const float*)d_in[2];
    const float* lbg = (const float*)d_in[3];
    const float* lbb = (const float*)d_in[4];
    const float* Wq  = (const float*)d_in[5];
    const float* bq  = (const float*)d_in[6];
    const float* Wk  = (const float*)d_in[7];
    const float* Wv  = (const float*)d_in[8];
    const float* bv  = (const float*)d_in[9];
    const float* Wc  = (const float*)d_in[10];
    const float* bc  = (const float*)d_in[11];
    const float* Wp  = (const float*)d_in[12];
    const float* bp  = (const float*)d_in[13];
    const float* Wo  = (const float*)d_in[14];
    const float* bo  = (const float*)d_in[15];
    float* out = (float*)d_out;
    us* wsu = (us*)d_ws;

    const size_t NM = (size_t)MROWS * DIMS;      // 2M elements
    us* lnAbf = wsu;                 // 4MB
    us* lnBbf = wsu + NM;            // 4MB (aliases gattbf)
    us* gattbf = lnBbf;
    us* qbf   = wsu + 2 * NM;        // 4MB ┐ comb (8MB)
    us* kbf   = wsu + 3 * NM;        // 4MB ┘
    us* vbf   = wsu + 4 * NM;        // 4MB
    us* combbf = qbf;                // [2048,2048] bf16
    us* Wqbf  = wsu + 5 * NM;
    us* Wkbf  = Wqbf + DIMS * DIMS;
    us* Wvbf  = Wkbf + DIMS * DIMS;
    us* Wcbf  = Wvbf + DIMS * DIMS;
    us* Wobf  = Wcbf + DIMS * DIMS;  // 2M elements
    float* partials = (float*)(Wobf + 2 * DIMS * DIMS);
    float* spanbuf  = partials + 16;

    // weight conversion
    cvt_kernel<<<1024, 256, 0, stream>>>(Wq, Wqbf);
    cvt_kernel<<<1024, 256, 0, stream>>>(Wk, Wkbf);
    cvt_kernel<<<1024, 256, 0, stream>>>(Wv, Wvbf);
    cvt_kernel<<<1024, 256, 0, stream>>>(Wc, Wcbf);
    cvt_kernel<<<2048, 256, 0, stream>>>(Wo, Wobf);

    ln2_kernel<<<MROWS, 256, 0, stream>>>(x, lag, lab, lbg, lbb, lnAbf, lnBbf);

    dim3 gg(DIMS / 64, MROWS / 64);  // (16, 32)
    gemm_bf16<1><<<gg, 256, 0, stream>>>(lnBbf, DIMS, Wqbf, DIMS, bq,      qbf, DIMS, DIMS);
    gemm_bf16<1><<<gg, 256, 0, stream>>>(lnBbf, DIMS, Wkbf, DIMS, nullptr, kbf, DIMS, DIMS);
    gemm_bf16<1><<<gg, 256, 0, stream>>>(lnBbf, DIMS, Wvbf, DIMS, bv,      vbf, DIMS, DIMS);

    dim3 ag(S_LEN / 64, NHEAD, BATCH);
    attn_mfma<0><<<ag, 256, 0, stream>>>(qbf, kbf, vbf, gattbf, DIMS, nullptr);

    // g_out -> comb[:, 1024:2048]  (bf16)
    gemm_bf16<1><<<gg, 256, 0, stream>>>(gattbf, DIMS, Wcbf, DIMS, bc, combbf + 1024, 2048, DIMS);

    span1_kernel<<<dim3(8, BATCH), 256, 0, stream>>>(combbf + 1024, Wp, partials);
    span2_kernel<<<1, 64, 0, stream>>>(partials, bp, spanbuf);

    // l_out -> comb[:, 0:1024]  (bf16)
    attn_mfma<1><<<ag, 256, 0, stream>>>(lnAbf, lnAbf, lnAbf, combbf, 2048, spanbuf);

    // out = comb @ Wo^T + bo   (K = 2048, f32 out)
    gemm_bf16<0><<<gg, 256, 0, stream>>>(combbf, 2048, Wobf, 2048, bo, out, DIMS, 2 * DIMS);
}

// Round 4
// 142.166 us; speedup vs baseline: 7.1174x; 1.2444x over previous
//
#include <hip/hip_runtime.h>
#include <math.h>

#define S_LEN 1024
#define DIMS  1024
#define NHEAD 16
#define HD    64
#define BATCH 2
#define MROWS (BATCH * S_LEN)   // 2048

typedef unsigned short us;
typedef __attribute__((ext_vector_type(8))) __bf16 bf8_t;
typedef __attribute__((ext_vector_type(8))) unsigned short us8_t;
typedef __attribute__((ext_vector_type(4))) unsigned short us4_t;
typedef __attribute__((ext_vector_type(4))) float f32x4;

static __device__ inline us f2bf(float f) {
    unsigned int u = __builtin_bit_cast(unsigned int, f);
    unsigned int r = u + 0x7fffu + ((u >> 16) & 1u);
    return (us)(r >> 16);
}
static __device__ inline float bf2f(us v) {
    unsigned int u = ((unsigned int)v) << 16;
    return __builtin_bit_cast(float, u);
}
static __device__ inline f32x4 mfma16(us8_t a, us8_t b, f32x4 c) {
    return __builtin_amdgcn_mfma_f32_16x16x32_bf16(
        __builtin_bit_cast(bf8_t, a), __builtin_bit_cast(bf8_t, b), c, 0, 0, 0);
}

// ---------------- combined f32 -> bf16 weight convert (1 launch) -----------
__global__ __launch_bounds__(256) void cvt5_kernel(
    const float* __restrict__ s0, const float* __restrict__ s1,
    const float* __restrict__ s2, const float* __restrict__ s3,
    const float* __restrict__ s4,
    us* __restrict__ d0, us* __restrict__ d1, us* __restrict__ d2,
    us* __restrict__ d3, us* __restrict__ d4)
{
    int bidx = blockIdx.x;   // 0..6143  (4x 1024 + 1x 2048 blocks)
    const float* src; us* dst; int blk;
    if (bidx < 1024)      { src = s0; dst = d0; blk = bidx; }
    else if (bidx < 2048) { src = s1; dst = d1; blk = bidx - 1024; }
    else if (bidx < 3072) { src = s2; dst = d2; blk = bidx - 2048; }
    else if (bidx < 4096) { src = s3; dst = d3; blk = bidx - 3072; }
    else                  { src = s4; dst = d4; blk = bidx - 4096; }
    size_t idx = (size_t)blk * 1024 + threadIdx.x * 4;
    float4 v = *(const float4*)(src + idx);
    us4_t ot;
    ot[0] = f2bf(v.x); ot[1] = f2bf(v.y); ot[2] = f2bf(v.z); ot[3] = f2bf(v.w);
    *(us4_t*)(dst + idx) = ot;
}

// ---------------- LayerNorm (both, bf16 out) ----------------
__global__ __launch_bounds__(256) void ln2_kernel(
    const float* __restrict__ x,
    const float* __restrict__ ga, const float* __restrict__ ba,
    const float* __restrict__ gb, const float* __restrict__ bb,
    us* __restrict__ outA, us* __restrict__ outB)
{
    int row = blockIdx.x;
    int t = threadIdx.x;
    const float* xr = x + (size_t)row * DIMS;
    float4 v = *(const float4*)(xr + t * 4);
    float s  = v.x + v.y + v.z + v.w;
    float s2 = v.x * v.x + v.y * v.y + v.z * v.z + v.w * v.w;
#pragma unroll
    for (int o = 32; o > 0; o >>= 1) {
        s  += __shfl_down(s, o, 64);
        s2 += __shfl_down(s2, o, 64);
    }
    __shared__ float rs[4], rs2[4];
    int wid = t >> 6, lane = t & 63;
    if (lane == 0) { rs[wid] = s; rs2[wid] = s2; }
    __syncthreads();
    float S0 = rs[0] + rs[1] + rs[2] + rs[3];
    float S2 = rs2[0] + rs2[1] + rs2[2] + rs2[3];
    float mean = S0 * (1.0f / DIMS);
    float var  = S2 * (1.0f / DIMS) - mean * mean;
    float inv  = 1.0f / sqrtf(var + 1e-5f);
    float4 vga = *(const float4*)(ga + t * 4);
    float4 vba = *(const float4*)(ba + t * 4);
    float4 vgb = *(const float4*)(gb + t * 4);
    float4 vbb = *(const float4*)(bb + t * 4);
    float nx = (v.x - mean) * inv, ny = (v.y - mean) * inv;
    float nz = (v.z - mean) * inv, nw = (v.w - mean) * inv;
    us4_t oa, ob;
    oa[0] = f2bf(nx * vga.x + vba.x); oa[1] = f2bf(ny * vga.y + vba.y);
    oa[2] = f2bf(nz * vga.z + vba.z); oa[3] = f2bf(nw * vga.w + vba.w);
    ob[0] = f2bf(nx * vgb.x + vbb.x); ob[1] = f2bf(ny * vgb.y + vbb.y);
    ob[2] = f2bf(nz * vgb.z + vbb.z); ob[3] = f2bf(nw * vgb.w + vbb.w);
    *(us4_t*)(outA + (size_t)row * DIMS + t * 4) = oa;
    *(us4_t*)(outB + (size_t)row * DIMS + t * 4) = ob;
}

// ---------------- bf16 MFMA GEMM body (prefetched K-slabs) ----------------
// C[M,N] = A[M,K] @ W[N,K]^T (+bias); 64x64 tile, 4 waves (2x2), 32x32/wave.
template <int OUTBF>
static __device__ __forceinline__ void gemm_body(
    const us* __restrict__ A, int lda,
    const us* __restrict__ W, int ldw,
    const float* __restrict__ bias,
    void* __restrict__ Cp, int ldc, int K,
    int bm, int bn, us* As, us* Bs)
{
    int tid = threadIdx.x;
    int w = tid >> 6, l = tid & 63, l15 = l & 15, lhi = l >> 4;
    int wr = w >> 1, wc = w & 1;
    f32x4 acc[2][2] = {{{0,0,0,0},{0,0,0,0}},{{0,0,0,0},{0,0,0,0}}};
    int srow = tid >> 3;            // 0..31
    int scol8 = tid & 7;            // 16B slot within row
    const us* Ap = A + (size_t)(bm + srow) * lda + scol8 * 8;
    const us* Wpt = W + (size_t)(bn + srow) * ldw + scol8 * 8;
    int sl = (scol8 ^ (srow & 7)) * 8;
    // prologue loads
    us8_t a0 = *(const us8_t*)(Ap);
    us8_t a1 = *(const us8_t*)(Ap + (size_t)32 * lda);
    us8_t b0 = *(const us8_t*)(Wpt);
    us8_t b1 = *(const us8_t*)(Wpt + (size_t)32 * ldw);
    for (int kt = 0; kt < K; kt += 64) {
        __syncthreads();
        *(us8_t*)&As[srow * 64 + sl] = a0;
        *(us8_t*)&As[(srow + 32) * 64 + sl] = a1;
        *(us8_t*)&Bs[srow * 64 + sl] = b0;
        *(us8_t*)&Bs[(srow + 32) * 64 + sl] = b1;
        __syncthreads();
        if (kt + 64 < K) {   // issue next slab; latency hides under MFMA below
            a0 = *(const us8_t*)(Ap + kt + 64);
            a1 = *(const us8_t*)(Ap + (size_t)32 * lda + kt + 64);
            b0 = *(const us8_t*)(Wpt + kt + 64);
            b1 = *(const us8_t*)(Wpt + (size_t)32 * ldw + kt + 64);
        }
#pragma unroll
        for (int kk = 0; kk < 2; ++kk) {
            us8_t af[2], bfr[2];
#pragma unroll
            for (int m = 0; m < 2; ++m) {
                int rowm = wr * 32 + m * 16 + l15;
                af[m] = *(const us8_t*)&As[rowm * 64 + (((kk * 4 + lhi)) ^ (rowm & 7)) * 8];
            }
#pragma unroll
            for (int n = 0; n < 2; ++n) {
                int rown = wc * 32 + n * 16 + l15;
                bfr[n] = *(const us8_t*)&Bs[rown * 64 + (((kk * 4 + lhi)) ^ (rown & 7)) * 8];
            }
#pragma unroll
            for (int m = 0; m < 2; ++m)
#pragma unroll
                for (int n = 0; n < 2; ++n)
                    acc[m][n] = mfma16(af[m], bfr[n], acc[m][n]);
        }
    }
    float bvv[2] = {0.f, 0.f};
    if (bias) {
#pragma unroll
        for (int n = 0; n < 2; ++n)
            bvv[n] = bias[bn + wc * 32 + n * 16 + l15];
    }
#pragma unroll
    for (int m = 0; m < 2; ++m) {
#pragma unroll
        for (int n = 0; n < 2; ++n) {
#pragma unroll
            for (int r = 0; r < 4; ++r) {
                int row = bm + wr * 32 + m * 16 + lhi * 4 + r;
                int col = bn + wc * 32 + n * 16 + l15;
                float val = acc[m][n][r] + bvv[n];
                if (OUTBF) ((us*)Cp)[(size_t)row * ldc + col] = f2bf(val);
                else       ((float*)Cp)[(size_t)row * ldc + col] = val;
            }
        }
    }
}

template <int OUTBF>
__global__ __launch_bounds__(256) void gemm_bf16(
    const us* __restrict__ A, int lda,
    const us* __restrict__ W, int ldw,
    const float* __restrict__ bias,
    void* __restrict__ Cp, int ldc, int K)
{
    __shared__ __align__(16) us As[64 * 64];
    __shared__ __align__(16) us Bs[64 * 64];
    gemm_body<OUTBF>(A, lda, W, ldw, bias, Cp, ldc, K,
                     blockIdx.y * 64, blockIdx.x * 64, As, Bs);
}

// q,k,v in one launch: blockIdx.x selects matrix (16 n-tiles each)
__global__ __launch_bounds__(256) void gemm_qkv(
    const us* __restrict__ A,
    const us* __restrict__ Wq, const us* __restrict__ Wk, const us* __restrict__ Wv,
    const float* __restrict__ bq, const float* __restrict__ bv,
    us* __restrict__ qo, us* __restrict__ ko, us* __restrict__ vo)
{
    __shared__ __align__(16) us As[64 * 64];
    __shared__ __align__(16) us Bs[64 * 64];
    int which = blockIdx.x >> 4;
    int bn = (blockIdx.x & 15) * 64, bm = blockIdx.y * 64;
    const us* W = (which == 0) ? Wq : ((which == 1) ? Wk : Wv);
    const float* bias = (which == 0) ? bq : ((which == 2) ? bv : nullptr);
    us* Out = (which == 0) ? qo : ((which == 1) ? ko : vo);
    gemm_body<1>(A, DIMS, W, DIMS, bias, Out, DIMS, DIMS, bm, bn, As, Bs);
}

// ---------------- MFMA flash attention, split-K, 8 waves ----------------
// Block: 512 threads. Wave w: wq = w&3 (q sub-tile of 16 rows), wk = w>>2
// (key half). Key tiles interleaved: half h processes tiles h, h+2, ...
// K/V staged double (one buffer per half) with issue-early prefetch.
// Final: merge the two halves' (m,l,o) partials through LDS.
template <int LOCAL>
__global__ __launch_bounds__(512) void attn_mfma(
    const us* __restrict__ Q, const us* __restrict__ K,
    const us* __restrict__ V, us* __restrict__ O, int ldo,
    const float* __restrict__ span)
{
    __shared__ __align__(16) us Ks[2][64 * 64];   // [half][key][d] swizzled
    __shared__ __align__(16) us Vt[2][64 * 64];   // [half][d][key] swizzled
    __shared__ __align__(16) us Ps[8][16 * 64];   // per-wave [q][key] swizzled

    int b = blockIdx.z, h = blockIdx.y;
    int q0blk = blockIdx.x * 64;
    int tid = threadIdx.x;
    int w = tid >> 6, l = tid & 63;
    int l15 = l & 15, lhi = l >> 4;
    int wq = w & 3, wk = w >> 2;

    float scale; int eff;
    if (LOCAL) { scale = span[1]; eff = (int)span[0]; }
    else       { scale = 1.0f / 64.0f; eff = S_LEN; }
    int ntiles = LOCAL ? ((eff + 63) >> 6) : 16;
    int nIter = (ntiles + 1) >> 1;

    int qrow = q0blk + wq * 16 + l15;
    const us* qptr = Q + ((size_t)(b * S_LEN + qrow)) * DIMS + h * HD + lhi * 8;
    us8_t qf[2];
    qf[0] = *(const us8_t*)(qptr);
    qf[1] = *(const us8_t*)(qptr + 32);

    f32x4 o[4] = {{0,0,0,0},{0,0,0,0},{0,0,0,0},{0,0,0,0}};
    float m_r[4] = {-1e30f, -1e30f, -1e30f, -1e30f};
    float l_r[4] = {0.f, 0.f, 0.f, 0.f};

    // staging role: threads [0,256) stage half 0's tiles, [256,512) half 1's
    int half = tid >> 8;
    int t0 = tid & 255;
    int krow = t0 >> 3, kcol8 = t0 & 7;
    int ksl = (kcol8 ^ (krow & 7)) * 8;
    int vkb = t0 & 15, vdb = t0 >> 4;
    const us* Kb = K + ((size_t)(b * S_LEN)) * DIMS + h * HD;
    const us* Vb = V + ((size_t)(b * S_LEN)) * DIMS + h * HD;

    us8_t kc0, kc1;
    us4_t vr0, vr1, vr2, vr3;
    if (half < ntiles) {   // prologue load (tile index == half)
        const us* kp = Kb + (size_t)(half * 64 + krow) * DIMS + kcol8 * 8;
        kc0 = *(const us8_t*)kp;
        kc1 = *(const us8_t*)(kp + (size_t)32 * DIMS);
        const us* vp = Vb + (size_t)(half * 64 + vkb * 4) * DIMS + vdb * 4;
        vr0 = *(const us4_t*)(vp);
        vr1 = *(const us4_t*)(vp + DIMS);
        vr2 = *(const us4_t*)(vp + 2 * DIMS);
        vr3 = *(const us4_t*)(vp + 3 * DIMS);
    }

    for (int i = 0; i < nIter; ++i) {
        __syncthreads();   // prior iteration's LDS reads done
        if (2 * i + half < ntiles) {
            *(us8_t*)&Ks[half][krow * 64 + ksl] = kc0;
            *(us8_t*)&Ks[half][(krow + 32) * 64 + ksl] = kc1;
#pragma unroll
            for (int j = 0; j < 4; ++j) {
                int d = vdb * 4 + j;
                us4_t wv;
                wv[0] = vr0[j]; wv[1] = vr1[j]; wv[2] = vr2[j]; wv[3] = vr3[j];
                int slot = (vkb >> 1) ^ (d & 7);
                *(us4_t*)&Vt[half][d * 64 + slot * 8 + (vkb & 1) * 4] = wv;
            }
        }
        __syncthreads();   // tiles visible
        int nt2 = 2 * (i + 1) + half;
        if (nt2 < ntiles) {   // issue next loads; latency hides under compute
            const us* kp = Kb + (size_t)(nt2 * 64 + krow) * DIMS + kcol8 * 8;
            kc0 = *(const us8_t*)kp;
            kc1 = *(const us8_t*)(kp + (size_t)32 * DIMS);
            const us* vp = Vb + (size_t)(nt2 * 64 + vkb * 4) * DIMS + vdb * 4;
            vr0 = *(const us4_t*)(vp);
            vr1 = *(const us4_t*)(vp + DIMS);
            vr2 = *(const us4_t*)(vp + 2 * DIMS);
            vr3 = *(const us4_t*)(vp + 3 * DIMS);
        }
        int kt = 2 * i + wk;
        if (kt < ntiles) {
            // ---- S = Q @ K^T ----
            f32x4 s4[4] = {{0,0,0,0},{0,0,0,0},{0,0,0,0},{0,0,0,0}};
            __builtin_amdgcn_s_setprio(1);
#pragma unroll
            for (int kk = 0; kk < 2; ++kk) {
#pragma unroll
                for (int n = 0; n < 4; ++n) {
                    int key = n * 16 + l15;
                    int slot = (kk * 4 + lhi) ^ (key & 7);
                    us8_t bk = *(const us8_t*)&Ks[wk][key * 64 + slot * 8];
                    s4[n] = mfma16(qf[kk], bk, s4[n]);
                }
            }
            __builtin_amdgcn_s_setprio(0);
#pragma unroll
            for (int n = 0; n < 4; ++n) {
                s4[n] *= scale;
                if (LOCAL) {
                    int key = kt * 64 + n * 16 + l15;
                    if (key >= eff) {
                        s4[n][0] = -1e30f; s4[n][1] = -1e30f;
                        s4[n][2] = -1e30f; s4[n][3] = -1e30f;
                    }
                }
            }
            // ---- online softmax (defer-max, THR=8) ----
            float tm[4];
#pragma unroll
            for (int r = 0; r < 4; ++r)
                tm[r] = fmaxf(fmaxf(s4[0][r], s4[1][r]), fmaxf(s4[2][r], s4[3][r]));
#pragma unroll
            for (int msk = 1; msk <= 8; msk <<= 1) {
#pragma unroll
                for (int r = 0; r < 4; ++r)
                    tm[r] = fmaxf(tm[r], __shfl_xor(tm[r], msk, 64));
            }
            bool upd = (tm[0] > m_r[0] + 8.f) || (tm[1] > m_r[1] + 8.f) ||
                       (tm[2] > m_r[2] + 8.f) || (tm[3] > m_r[3] + 8.f);
            if (upd) {
                float fac[4];
#pragma unroll
                for (int r = 0; r < 4; ++r) {
                    float mn = fmaxf(m_r[r], tm[r]);
                    fac[r] = __expf(m_r[r] - mn);
                    m_r[r] = mn;
                    l_r[r] *= fac[r];
                }
#pragma unroll
                for (int n = 0; n < 4; ++n) {
                    o[n][0] *= fac[0]; o[n][1] *= fac[1];
                    o[n][2] *= fac[2]; o[n][3] *= fac[3];
                }
            }
            float ladd[4] = {0.f, 0.f, 0.f, 0.f};
#pragma unroll
            for (int n = 0; n < 4; ++n) {
                int col = n * 16 + l15;
                int slotbase = col >> 3;
#pragma unroll
                for (int r = 0; r < 4; ++r) {
                    float p = __expf(s4[n][r] - m_r[r]);
                    ladd[r] += p;
                    int qlr = lhi * 4 + r;
                    int slot = slotbase ^ (qlr & 7);
                    Ps[w][qlr * 64 + slot * 8 + (col & 7)] = f2bf(p);
                }
            }
#pragma unroll
            for (int msk = 1; msk <= 8; msk <<= 1) {
#pragma unroll
                for (int r = 0; r < 4; ++r)
                    ladd[r] += __shfl_xor(ladd[r], msk, 64);
            }
#pragma unroll
            for (int r = 0; r < 4; ++r) l_r[r] += ladd[r];

            // ---- O += P @ V (Ps is wave-private: no barrier needed) ----
            __builtin_amdgcn_s_setprio(1);
#pragma unroll
            for (int kk = 0; kk < 2; ++kk) {
                int slot = (kk * 4 + lhi) ^ (l15 & 7);
                us8_t pa = *(const us8_t*)&Ps[w][l15 * 64 + slot * 8];
#pragma unroll
                for (int n = 0; n < 4; ++n) {
                    int d = n * 16 + l15;
                    int vslot = (kk * 4 + lhi) ^ (d & 7);
                    us8_t vb = *(const us8_t*)&Vt[wk][d * 64 + vslot * 8];
                    o[n] = mfma16(pa, vb, o[n]);
                }
            }
            __builtin_amdgcn_s_setprio(0);
        }
    }

    // ---- merge the two key-halves' partials ----
    __syncthreads();   // all compute done; Ks/Vt reusable as f32 merge buffers
    float* obuf = (float*)&Ks[0][0];    // [4 wq][16 row][64 col] f32 = 16KB
    float* mlb  = (float*)&Vt[0][0];    // [4 wq][16 row][2] f32
    if (wk == 1) {
#pragma unroll
        for (int n = 0; n < 4; ++n)
#pragma unroll
            for (int r = 0; r < 4; ++r)
                obuf[wq * 1024 + (lhi * 4 + r) * 64 + n * 16 + l15] = o[n][r];
        if (l15 == 0) {
#pragma unroll
            for (int r = 0; r < 4; ++r) {
                mlb[wq * 32 + (lhi * 4 + r) * 2 + 0] = m_r[r];
                mlb[wq * 32 + (lhi * 4 + r) * 2 + 1] = l_r[r];
            }
        }
    }
    __syncthreads();
    if (wk == 0) {
        float f0[4], f1[4], rcp[4];
#pragma unroll
        for (int r = 0; r < 4; ++r) {
            int row = lhi * 4 + r;
            float m1 = mlb[wq * 32 + row * 2 + 0];
            float l1 = mlb[wq * 32 + row * 2 + 1];
            float ms = fmaxf(m_r[r], m1);
            f0[r] = __expf(m_r[r] - ms);
            f1[r] = __expf(m1 - ms);
            rcp[r] = 1.0f / (l_r[r] * f0[r] + l1 * f1[r]);
        }
#pragma unroll
        for (int n = 0; n < 4; ++n) {
#pragma unroll
            for (int r = 0; r < 4; ++r) {
                int row = q0blk + wq * 16 + lhi * 4 + r;
                float val = (o[n][r] * f0[r] +
                             obuf[wq * 1024 + (lhi * 4 + r) * 64 + n * 16 + l15] * f1[r]) * rcp[r];
                if (LOCAL && row >= eff) val = 0.0f;
                O[((size_t)(b * S_LEN + row)) * ldo + h * HD + n * 16 + l15] = f2bf(val);
            }
        }
    }
}

// ---------------- span predictor ----------------
__global__ __launch_bounds__(256) void span1_kernel(
    const us* __restrict__ gout, const float* __restrict__ Wp,
    float* __restrict__ partials)
{
    int slice = blockIdx.x;   // 0..7 (128 rows each)
    int b = blockIdx.y;
    int t = threadIdx.x;
    float4 wp = *(const float4*)(Wp + t * 4);
    float acc = 0;
    int s0 = slice * 128;
    for (int s = s0; s < s0 + 128; ++s) {
        us4_t g = *(const us4_t*)(gout + (size_t)(b * S_LEN + s) * 2048 + t * 4);
        acc += bf2f(g[0]) * wp.x + bf2f(g[1]) * wp.y + bf2f(g[2]) * wp.z + bf2f(g[3]) * wp.w;
    }
#pragma unroll
    for (int o = 32; o > 0; o >>= 1) acc += __shfl_down(acc, o, 64);
    __shared__ float r[4];
    int wid = t >> 6, lane = t & 63;
    if (lane == 0) r[wid] = acc;
    __syncthreads();
    if (t == 0) partials[b * 8 + slice] = r[0] + r[1] + r[2] + r[3];
}

__global__ void span2_kernel(const float* __restrict__ partials,
                             const float* __restrict__ bp,
                             float* __restrict__ spanbuf)
{
    if (threadIdx.x == 0 && blockIdx.x == 0) {
        float l0 = 0, l1 = 0;
        for (int i = 0; i < 8; ++i) { l0 += partials[i]; l1 += partials[8 + i]; }
        l0 = l0 * (1.0f / 1024.0f) + bp[0];
        l1 = l1 * (1.0f / 1024.0f) + bp[0];
        float s0 = 1.0f / (1.0f + expf(-l0));
        float s1 = 1.0f / (1.0f + expf(-l1));
        float sm = 0.5f * (s0 + s1);
        int sl = (int)floorf(1024.0f * sm);
        int eff = sl; if (eff > 1024) eff = 1024; if (eff < 1) eff = 1;
        float temp = 1.0f + 0.01f * (1.0f - sm);
        spanbuf[0] = (float)eff;
        spanbuf[1] = 0.35355339059327378f / temp;  // 64^-0.25 / temp
    }
}

extern "C" void kernel_launch(void* const* d_in, const int* in_sizes, int n_in,
                              void* d_out, int out_size, void* d_ws, size_t ws_size,
                              hipStream_t stream)
{
    (void)in_sizes; (void)n_in; (void)out_size; (void)ws_size;
    const float* x   = (const float*)d_in[0];
    const float* lag = (const float*)d_in[1];
    const float* lab = (const float*)d_in[2];
    const float* lbg = (const float*)d_in[3];
    const float* lbb = (const float*)d_in[4];
    const float* Wq  = (const float*)d_in[5];
    const float* bq  = (const float*)d_in[6];
    const float* Wk  = (const float*)d_in[7];
    const float* Wv  = (const float*)d_in[8];
    const float* bv  = (const float*)d_in[9];
    const float* Wc  = (const float*)d_in[10];
    const float* bc  = (const float*)d_in[11];
    const float* Wp  = (const float*)d_in[12];
    const float* bp  = (const float*)d_in[13];
    const float* Wo  = (const float*)d_in[14];
    const float* bo  = (const float*)d_in[15];
    float* out = (float*)d_out;
    us* wsu = (us*)d_ws;

    const size_t NM = (size_t)MROWS * DIMS;      // 2M elements
    us* lnAbf = wsu;                 // 4MB
    us* lnBbf = wsu + NM;            // 4MB (aliases gattbf)
    us* gattbf = lnBbf;
    us* qbf   = wsu + 2 * NM;        // 4MB ┐ comb (8MB)
    us* kbf   = wsu + 3 * NM;        // 4MB ┘
    us* vbf   = wsu + 4 * NM;        // 4MB
    us* combbf = qbf;                // [2048,2048] bf16
    us* Wqbf  = wsu + 5 * NM;
    us* Wkbf  = Wqbf + DIMS * DIMS;
    us* Wvbf  = Wkbf + DIMS * DIMS;
    us* Wcbf  = Wvbf + DIMS * DIMS;
    us* Wobf  = Wcbf + DIMS * DIMS;  // 2M elements
    float* partials = (float*)(Wobf + 2 * DIMS * DIMS);
    float* spanbuf  = partials + 16;

    // all weight conversions in one launch
    cvt5_kernel<<<6144, 256, 0, stream>>>(Wq, Wk, Wv, Wc, Wo,
                                          Wqbf, Wkbf, Wvbf, Wcbf, Wobf);

    ln2_kernel<<<MROWS, 256, 0, stream>>>(x, lag, lab, lbg, lbb, lnAbf, lnBbf);

    // q,k,v in one launch
    gemm_qkv<<<dim3(48, MROWS / 64), 256, 0, stream>>>(
        lnBbf, Wqbf, Wkbf, Wvbf, bq, bv, qbf, kbf, vbf);

    dim3 ag(S_LEN / 64, NHEAD, BATCH);
    attn_mfma<0><<<ag, 512, 0, stream>>>(qbf, kbf, vbf, gattbf, DIMS, nullptr);

    // g_out -> comb[:, 1024:2048]  (bf16)
    dim3 gg(DIMS / 64, MROWS / 64);
    gemm_bf16<1><<<gg, 256, 0, stream>>>(gattbf, DIMS, Wcbf, DIMS, bc, combbf + 1024, 2048, DIMS);

    span1_kernel<<<dim3(8, BATCH), 256, 0, stream>>>(combbf + 1024, Wp, partials);
    span2_kernel<<<1, 64, 0, stream>>>(partials, bp, spanbuf);

    // l_out -> comb[:, 0:1024]  (bf16)
    attn_mfma<1><<<ag, 512, 0, stream>>>(lnAbf, lnAbf, lnAbf, combbf, 2048, spanbuf);

    // out = comb @ Wo^T + bo   (K = 2048, f32 out)
    gemm_bf16<0><<<gg, 256, 0, stream>>>(combbf, 2048, Wobf, 2048, bo, out, DIMS, 2 * DIMS);
}